// Round 9
// baseline (153.214 us; speedup 1.0000x reference)
//
#include <hip/hip_runtime.h>
#include <math.h>

#define N_   4
#define C_   128
#define CO_  128
#define H_   96
#define W_   96
#define HW_  (H_*W_)
#define BN_EPS_ 1e-5f

typedef short bf16x8 __attribute__((ext_vector_type(8)));
typedef float f32x4  __attribute__((ext_vector_type(4)));
typedef unsigned short ushortx8 __attribute__((ext_vector_type(8)));

__device__ __forceinline__ unsigned short f2bf_rne(float f) {
    unsigned u = __builtin_bit_cast(unsigned, f);
    return (unsigned short)((u + 0x7fffu + ((u >> 16) & 1u)) >> 16);
}
__device__ __forceinline__ float bf2f(unsigned short s) {
    unsigned u = ((unsigned)s) << 16;
    return __builtin_bit_cast(float, u);
}

// ---------------------------------------------------------------------------
// ws layout (float offsets):
//   convout : 995328 f                     @ 0
//   out_pre : 4718592 ushort (2359296 f)   @ 995328    [n][o][hw] bf16
//   (bn slot retired -- stats now computed per-block in k_bn)
//   wjT     : 36864 ushort (18432 f)       @ 3354880   [kk][k_hi][j32][k_lo8]
//   wTA     : 147456 ushort (73728 f)      @ 3373312   [kk][k_hi][o128][k_lo8]
//   xb      : 4718592 ushort (2359296 f)   @ 3447040   [n][hw][c] channel-last bf16
//   part    : 294912 f                     @ 5806336   [s2*o128][tile1152] BN partials
// NOTE: k_prep/k_offconv/k_gemm are FROZEN at the r8-passing bits. Two codegen
// perturbations of the gemm/offconv code (r2 launch_bounds, r7 phase-0 fusion)
// flipped correctness; only the independent k_bn tail is modified this round
// (k_red merged in as a per-block prologue -> one fewer kernel boundary).
// ---------------------------------------------------------------------------
#define WS_CONVOUT 0
#define WS_OUTPRE  995328
#define WS_WJT     3354880
#define WS_WTA     3373312
#define WS_XB      3447040
#define WS_PART    5806336

// K ordering: K = ktap*128 + c, chunk kk of 32: ktap=kk>>2, c=(kk&3)*32+k_hi*8+k_lo.

// XCD-aware bijective swizzle for 1152-tile grids (1152 = 8 XCDs * 144):
// XCD x owns tiles [x*144, (x+1)*144) = half of one image -> xb slice (~1.2MB)
// + wTA (288KB) are L2-resident per XCD.
__device__ __forceinline__ int swz_tile(int bid) {
    return (bid & 7) * 144 + (bid >> 3);
}

// k_prep: blocks [0,1152) transpose x -> channel-last bf16; [1152,1872) repack weights.
// [FROZEN r8]
__global__ __launch_bounds__(256)
void k_prep(const float* __restrict__ x,
            const float* __restrict__ offw, const float* __restrict__ modw,
            const float* __restrict__ weight,
            unsigned short* __restrict__ xb,
            unsigned short* __restrict__ wjT, unsigned short* __restrict__ wTA) {
    const int b = blockIdx.x;
    const int t = threadIdx.x;
    if (b < 1152) {
        __shared__ __align__(16) unsigned short lds[32][136];
        const int tile = swz_tile(b);           // write xb tiles on the XCD that reads them
        const int n = tile / 288, pix0 = (tile % 288) * 32;
        #pragma unroll
        for (int i = 0; i < 4; ++i) {
            const int c  = i*32 + (t >> 3);
            const int pb = (t & 7) * 4;
            const float4 v = *(const float4*)&x[((size_t)(n*C_ + c))*HW_ + pix0 + pb];
            lds[pb+0][c] = f2bf_rne(v.x);
            lds[pb+1][c] = f2bf_rne(v.y);
            lds[pb+2][c] = f2bf_rne(v.z);
            lds[pb+3][c] = f2bf_rne(v.w);
        }
        __syncthreads();
        #pragma unroll
        for (int it = 0; it < 2; ++it) {
            const int e = it*256 + t;
            const int p = e >> 4, g = e & 15;
            const uint4 v = *(const uint4*)&lds[p][g*8];
            *(uint4*)&xb[((size_t)n*HW_ + pix0 + p)*C_ + g*8] = v;
        }
    } else {
        const int e = (b - 1152)*256 + t;
        if (e < 36864) {
            const int k_lo = e & 7, j = (e >> 3) & 31, k_hi = (e >> 8) & 3, kk = e >> 10;
            const int c  = (kk & 3)*32 + k_hi*8 + k_lo;
            const int kt = kk >> 2;
            float v = 0.0f;
            if (j < 18)      v = offw[(j*C_ + c)*9 + kt];
            else if (j < 27) v = modw[((j-18)*C_ + c)*9 + kt];
            wjT[e] = f2bf_rne(v);
        } else {
            const int e2 = e - 36864;
            const int k_lo = e2 & 7, o = (e2 >> 3) & 127, k_hi = (e2 >> 10) & 3, kk = e2 >> 12;
            const int c  = (kk & 3)*32 + k_hi*8 + k_lo;
            const int kt = kk >> 2;
            wTA[e2] = f2bf_rne(weight[(o*C_ + c)*9 + kt]);
        }
    }
}

// k_offconv: K-split MFMA conv. Block = 32 px; 4 waves = 2 px-halves x 2 K-halves.
// grid 1152 -> 4608 waves (~18/CU). LDS pairwise reduction at the end. [FROZEN r6]
__global__ __launch_bounds__(256)
void k_offconv(const unsigned short* __restrict__ xb,
               const unsigned short* __restrict__ wjT,
               const float* __restrict__ offb, const float* __restrict__ modb,
               float* __restrict__ convout) {
    __shared__ float red[2][64][8];   // 4KB
    const int t = threadIdx.x;
    const int wid = t >> 6, lane = t & 63, quad = lane >> 4, l16 = lane & 15;
    const int ph = wid & 1, kh = wid >> 1;
    const int tile = swz_tile(blockIdx.x);
    const int n = tile / 288, p0 = (tile - n*288)*32;
    const int pix = p0 + ph*16 + l16;
    const int h = pix / W_, w = pix - h*W_;
    const unsigned short* xq = xb + ((size_t)n*HW_)*C_ + quad*8;

    f32x4 acc0 = {0.f,0.f,0.f,0.f};
    f32x4 acc1 = {0.f,0.f,0.f,0.f};

    #pragma unroll
    for (int i = 0; i < 18; ++i) {
        const int kk = kh*18 + i;
        const int kt = kk >> 2, s = kk & 3;
        const int dy = kt/3 - 1, dx = kt%3 - 1;
        const int y = h + dy, xx = w + dx;
        const bool valid = ((unsigned)y < H_) & ((unsigned)xx < W_);
        const uint4 braw = valid ? *(const uint4*)(xq + (size_t)(y*W_ + xx)*C_ + s*32)
                                 : make_uint4(0u,0u,0u,0u);
        const unsigned short* ap = wjT + (size_t)kk*1024 + quad*256 + l16*8;
        const bf16x8 a0 = *(const bf16x8*)(ap);
        const bf16x8 a1 = *(const bf16x8*)(ap + 128);
        const bf16x8 bfr = __builtin_bit_cast(bf16x8, braw);
        acc0 = __builtin_amdgcn_mfma_f32_16x16x32_bf16(a0, bfr, acc0, 0, 0, 0);
        acc1 = __builtin_amdgcn_mfma_f32_16x16x32_bf16(a1, bfr, acc1, 0, 0, 0);
    }

    if (kh == 1) {
        *(f32x4*)&red[ph][lane][0] = acc0;
        *(f32x4*)&red[ph][lane][4] = acc1;
    }
    __syncthreads();
    if (kh == 0) {
        const f32x4 r0 = *(const f32x4*)&red[ph][lane][0];
        const f32x4 r1 = *(const f32x4*)&red[ph][lane][4];
        #pragma unroll
        for (int r = 0; r < 4; ++r) {
            const int j0 = quad*4 + r;
            convout[((size_t)n*27 + j0)*HW_ + pix] =
                acc0[r] + r0[r] + (j0 < 18 ? offb[j0] : modb[j0-18]);
            const int j1 = 16 + quad*4 + r;
            if (j1 < 27)
                convout[((size_t)n*27 + j1)*HW_ + pix] = acc1[r] + r1[r] + modb[j1-18];
        }
    }
}

// k_gemm: r1/r6 fused tap-major pipelined loop + no-atomic partials epilogue.
// [FROZEN r6 — do not perturb codegen context]
__global__ __launch_bounds__(256)
void k_gemm(const unsigned short* __restrict__ xb,
            const float* __restrict__ convout,
            const unsigned short* __restrict__ wTA,
            unsigned short* __restrict__ out_pre,
            float* __restrict__ part) {
    __shared__ int4   midx[9][32];                            // 4.5KB corner byte offsets
    __shared__ float4 mwgt[9][32];                            // 4.5KB corner weights (mask folded)
    __shared__ __align__(16) unsigned short Blds[2][16][32][8]; // 16KB [buf][c4*quad4][px32^swz][8ch]

    const int t = threadIdx.x;
    const int wid = t >> 6, lane = t & 63, quad = lane >> 4, l16 = lane & 15;
    const int tile = swz_tile(blockIdx.x);
    const int n = tile / 288, p0 = (tile - n*288)*32;
    const char* xbn = (const char*)(xb + (size_t)n*HW_*C_);
    const float* co = convout + (size_t)n*27*HW_;

    // ---- Phase A: bilinear metadata for 9 taps x 32 pixels ----
    for (int it = t; it < 288; it += 256) {
        const int kt = it >> 5, p = it & 31;
        const int pix = p0 + p;
        const int h = pix / W_, w = pix - h*W_;
        const float offy = co[(2*kt  )*HW_ + pix];
        const float offx = co[(2*kt+1)*HW_ + pix];
        const float mraw = co[(18+kt )*HW_ + pix];
        const float m = 2.0f / (1.0f + __expf(-mraw));
        const float sy = offy + (float)(h + kt/3 - 1);
        const float sx = offx + (float)(w + kt%3 - 1);
        const float y0f = floorf(sy), x0f = floorf(sx);
        const float wy1 = sy - y0f, wx1 = sx - x0f;
        const float wyv[2] = {1.0f - wy1, wy1};
        const float wxv[2] = {1.0f - wx1, wx1};
        const float yfv[2] = {y0f, y0f + 1.0f};
        const float xfv[2] = {x0f, x0f + 1.0f};
        int   ii[4]; float ww[4];
        #pragma unroll
        for (int cy = 0; cy < 2; ++cy)
            #pragma unroll
            for (int cx = 0; cx < 2; ++cx) {
                const bool vld = (yfv[cy] >= 0.f) & (yfv[cy] <= (float)(H_-1)) &
                                 (xfv[cx] >= 0.f) & (xfv[cx] <= (float)(W_-1));
                const int yi = (int)fminf(fmaxf(yfv[cy], 0.f), (float)(H_-1));
                const int xi = (int)fminf(fmaxf(xfv[cx], 0.f), (float)(W_-1));
                ii[cy*2+cx] = (yi*W_ + xi)*C_*2;   // byte offset into xb row space
                ww[cy*2+cx] = vld ? wyv[cy]*wxv[cx]*m : 0.f;
            }
        midx[kt][p] = make_int4(ii[0], ii[1], ii[2], ii[3]);
        mwgt[kt][p] = make_float4(ww[0], ww[1], ww[2], ww[3]);
    }
    __syncthreads();

    f32x4 acc[2][2];
    #pragma unroll
    for (int i = 0; i < 2; ++i)
        #pragma unroll
        for (int j = 0; j < 2; ++j) acc[i][j] = (f32x4){0.f,0.f,0.f,0.f};

    // gather/blend thread mapping: px gp = t>>3, ch-group gg = t&7 (16 ch = 32B)
    const int gp = t >> 3;
    const int gg = t & 7;
    const int cb = gg >> 1;          // chunk-in-tap 0..3
    const int q2 = (gg & 1) * 2;     // quad base 0 or 2
    const char* xgg = xbn + gg*32;   // channel-slice base

    uint4 rr[4][2];                  // 4 corners x 32B in flight
    float4 wgn;

    auto gather_issue = [&](int kt) {
        const int4 ib = midx[kt][gp];
        wgn = mwgt[kt][gp];
        rr[0][0] = *(const uint4*)(xgg + ib.x); rr[0][1] = *(const uint4*)(xgg + ib.x + 16);
        rr[1][0] = *(const uint4*)(xgg + ib.y); rr[1][1] = *(const uint4*)(xgg + ib.y + 16);
        rr[2][0] = *(const uint4*)(xgg + ib.z); rr[2][1] = *(const uint4*)(xgg + ib.z + 16);
        rr[3][0] = *(const uint4*)(xgg + ib.w); rr[3][1] = *(const uint4*)(xgg + ib.w + 16);
    };
    auto blend_store = [&](int buf) {
        #pragma unroll
        for (int h = 0; h < 2; ++h) {
            const unsigned short* c0 = (const unsigned short*)&rr[0][h];
            const unsigned short* c1 = (const unsigned short*)&rr[1][h];
            const unsigned short* c2 = (const unsigned short*)&rr[2][h];
            const unsigned short* c3 = (const unsigned short*)&rr[3][h];
            ushortx8 v;
            #pragma unroll
            for (int j = 0; j < 8; ++j) {
                const float f = wgn.x*bf2f(c0[j]) + wgn.y*bf2f(c1[j])
                              + wgn.z*bf2f(c2[j]) + wgn.w*bf2f(c3[j]);
                v[j] = (unsigned short)(__builtin_bit_cast(unsigned, f) >> 16);
            }
            const int row = cb*4 + q2 + h;                    // [0,16)
            *(ushortx8*)&Blds[buf][row][gp ^ (row & 7)][0] = v;  // px-XOR: conflict-free
        }
    };

    // prologue: stage tap 0
    gather_issue(0);
    blend_store(0);
    __syncthreads();

    #pragma unroll 2
    for (int kt = 0; kt < 9; ++kt) {
        const int buf = kt & 1;
        // A fragments FIRST so the MFMA vmcnt-wait doesn't drain the gathers
        const unsigned short* ap = wTA + (size_t)kt*16384 + quad*1024 + (wid*32 + l16)*8;
        bf16x8 a[4][2];
        #pragma unroll
        for (int c = 0; c < 4; ++c) {
            a[c][0] = *(const bf16x8*)(ap + c*4096);
            a[c][1] = *(const bf16x8*)(ap + c*4096 + 128);
        }
        if (kt < 8) gather_issue(kt + 1);     // in flight across the MFMA block
        #pragma unroll
        for (int c = 0; c < 4; ++c) {
            const int row = c*4 + quad;
            const int sw = row & 7;
            const bf16x8 b0 = *(const bf16x8*)&Blds[buf][row][l16 ^ sw][0];
            const bf16x8 b1 = *(const bf16x8*)&Blds[buf][row][16 + (l16 ^ sw)][0];
            acc[0][0] = __builtin_amdgcn_mfma_f32_16x16x32_bf16(a[c][0], b0, acc[0][0], 0, 0, 0);
            acc[0][1] = __builtin_amdgcn_mfma_f32_16x16x32_bf16(a[c][0], b1, acc[0][1], 0, 0, 0);
            acc[1][0] = __builtin_amdgcn_mfma_f32_16x16x32_bf16(a[c][1], b0, acc[1][0], 0, 0, 0);
            acc[1][1] = __builtin_amdgcn_mfma_f32_16x16x32_bf16(a[c][1], b1, acc[1][1], 0, 0, 0);
        }
        if (kt < 8) blend_store(buf ^ 1);     // waits vmcnt(0) here, after MFMAs
        __syncthreads();                      // single barrier per tap (2-buffer safe)
    }

    // ---- epilogue: store pre-BN bf16; BN partials to private slots (no atomics) ----
    const int bid = blockIdx.x;
    #pragma unroll
    for (int mt = 0; mt < 2; ++mt) {
        #pragma unroll
        for (int r = 0; r < 4; ++r) {
            const int o = wid*32 + mt*16 + quad*4 + r;
            const float v0 = acc[mt][0][r];
            const float v1 = acc[mt][1][r];
            unsigned short* op = out_pre + ((size_t)n*CO_ + o)*HW_ + p0 + l16;
            op[0]  = f2bf_rne(v0);
            op[16] = f2bf_rne(v1);
            float s1 = v0 + v1, s2 = v0*v0 + v1*v1;
            #pragma unroll
            for (int d = 1; d < 16; d <<= 1) {
                s1 += __shfl_xor(s1, d);
                s2 += __shfl_xor(s2, d);
            }
            if (l16 == 0) {
                part[(size_t)o*1152 + bid]         = s1;
                part[(size_t)(128 + o)*1152 + bid] = s2;
            }
        }
    }
}

// k_bn v2: k_red MERGED IN. Each block spans 2048 contiguous out elements
// (all within one n; 2048 < HW so at most TWO output channels oa/ob). The 4
// waves redundantly reduce the <=4 needed part rows (oa/ob x sum/sq), 18
// coalesced loads/lane from the L2-resident 1.2MB part buffer, then apply
// BN+ReLU exactly as before. Removes the k_red launch + one kernel boundary.
__global__ __launch_bounds__(256)
void k_bn(const unsigned short* __restrict__ out_pre,
          const float* __restrict__ part,
          const float* __restrict__ gamma, const float* __restrict__ beta,
          float* __restrict__ out) {
    __shared__ float sred[4];
    const int t = threadIdx.x, b = blockIdx.x;
    const int rem = (b * 2048) % (CO_ * HW_);   // within-n element offset
    const int oa  = rem / HW_;
    const int ob  = (rem + 2047) / HW_;         // oa or oa+1 (block never straddles n)
    const int wv = t >> 6, col = t & 63;
    const int ow  = (wv < 2) ? oa : ob;
    const int row = (wv & 1) ? (128 + ow) : ow;
    float s = 0.f;
    for (int i = col; i < 1152; i += 64) s += part[(size_t)row * 1152 + i];
    #pragma unroll
    for (int d = 1; d < 64; d <<= 1) s += __shfl_xor(s, d);
    if (col == 0) sred[wv] = s;
    __syncthreads();

    const int e8 = b*256 + t;
    const int o = ((e8*8) / HW_) % CO_;
    const float bsum = (o == oa) ? sred[0] : sred[2];
    const float bsq  = (o == oa) ? sred[1] : sred[3];
    const float invM = 1.0f / (float)(N_*HW_);
    const float mean = bsum * invM;
    const float var  = bsq * invM - mean*mean;
    const float gsc  = gamma[o] * rsqrtf(var + BN_EPS_);
    const float sh   = beta[o] - mean * gsc;
    const uint4 v = ((const uint4*)out_pre)[e8];
    const unsigned short* us = (const unsigned short*)&v;
    float4 o0, o1;
    o0.x = fmaxf(bf2f(us[0])*gsc + sh, 0.f);
    o0.y = fmaxf(bf2f(us[1])*gsc + sh, 0.f);
    o0.z = fmaxf(bf2f(us[2])*gsc + sh, 0.f);
    o0.w = fmaxf(bf2f(us[3])*gsc + sh, 0.f);
    o1.x = fmaxf(bf2f(us[4])*gsc + sh, 0.f);
    o1.y = fmaxf(bf2f(us[5])*gsc + sh, 0.f);
    o1.z = fmaxf(bf2f(us[6])*gsc + sh, 0.f);
    o1.w = fmaxf(bf2f(us[7])*gsc + sh, 0.f);
    ((float4*)out)[e8*2]     = o0;
    ((float4*)out)[e8*2 + 1] = o1;
}

extern "C" void kernel_launch(void* const* d_in, const int* in_sizes, int n_in,
                              void* d_out, int out_size, void* d_ws, size_t ws_size,
                              hipStream_t stream) {
    const float* x      = (const float*)d_in[0];
    const float* offw   = (const float*)d_in[1];
    const float* offb   = (const float*)d_in[2];
    const float* modw   = (const float*)d_in[3];
    const float* modb   = (const float*)d_in[4];
    const float* weight = (const float*)d_in[5];
    const float* gamma  = (const float*)d_in[7];
    const float* beta   = (const float*)d_in[8];
    float* out = (float*)d_out;

    float* wsf = (float*)d_ws;
    float*          convout = wsf + WS_CONVOUT;
    unsigned short* out_pre = (unsigned short*)(wsf + WS_OUTPRE);
    unsigned short* wjT     = (unsigned short*)(wsf + WS_WJT);
    unsigned short* wTA     = (unsigned short*)(wsf + WS_WTA);
    unsigned short* xb      = (unsigned short*)(wsf + WS_XB);
    float*          part    = wsf + WS_PART;

    k_prep<<<1872, 256, 0, stream>>>(x, offw, modw, weight, xb, wjT, wTA);
    k_offconv<<<1152, 256, 0, stream>>>(xb, wjT, offb, modb, convout);
    k_gemm<<<1152, 256, 0, stream>>>(xb, convout, wTA, out_pre, part);
    k_bn<<<2304, 256, 0, stream>>>(out_pre, part, gamma, beta, out);
}

// Round 10
// 146.262 us; speedup vs baseline: 1.0475x; 1.0475x over previous
//
#include <hip/hip_runtime.h>
#include <math.h>

#define N_   4
#define C_   128
#define CO_  128
#define H_   96
#define W_   96
#define HW_  (H_*W_)
#define BN_EPS_ 1e-5f

typedef short bf16x8 __attribute__((ext_vector_type(8)));
typedef float f32x4  __attribute__((ext_vector_type(4)));
typedef unsigned short ushortx8 __attribute__((ext_vector_type(8)));

__device__ __forceinline__ unsigned short f2bf_rne(float f) {
    unsigned u = __builtin_bit_cast(unsigned, f);
    return (unsigned short)((u + 0x7fffu + ((u >> 16) & 1u)) >> 16);
}
__device__ __forceinline__ float bf2f(unsigned short s) {
    unsigned u = ((unsigned)s) << 16;
    return __builtin_bit_cast(float, u);
}

// ---------------------------------------------------------------------------
// ws layout (float offsets):
//   convout : 995328 f                     @ 0
//   out_pre : 4718592 ushort (2359296 f)   @ 995328    [n][o][hw] bf16
//   bn      : 256 f                        @ 3354624
//   wjT     : 36864 ushort (18432 f)       @ 3354880   [kk][k_hi][j32][k_lo8]
//   wTA     : 147456 ushort (73728 f)      @ 3373312   [kk][k_hi][o128][k_lo8]
//   xb      : 4718592 ushort (2359296 f)   @ 3447040   [n][hw][c] channel-last bf16
//   part    : 294912 f                     @ 5806336   [s2*o128][tile1152] BN partials
//
// SESSION MODEL (r9 post-mortem): dur_us = ~90us fixed harness poison fills
// (2 x 268MB fillBufferAligned inside the measured iteration) + ~58us ours:
// k_gemm ~30 + k_prep ~7 + k_offconv ~6 + k_red ~3 + k_bn ~5 + gaps ~1.5x4.
// Boundary gaps measured ~1.3us (r9 isolated them net of added work) ->
// fusion is not a lever. k_gemm interior is frozen-fragile (r2/r7 flips).
// This file is the r8-verified best (147.5us) restated verbatim.
// ---------------------------------------------------------------------------
#define WS_CONVOUT 0
#define WS_OUTPRE  995328
#define WS_BN      3354624
#define WS_WJT     3354880
#define WS_WTA     3373312
#define WS_XB      3447040
#define WS_PART    5806336

// K ordering: K = ktap*128 + c, chunk kk of 32: ktap=kk>>2, c=(kk&3)*32+k_hi*8+k_lo.

// XCD-aware bijective swizzle for 1152-tile grids (1152 = 8 XCDs * 144):
// XCD x owns tiles [x*144, (x+1)*144) = half of one image -> xb slice (~1.2MB)
// + wTA (288KB) are L2-resident per XCD.
__device__ __forceinline__ int swz_tile(int bid) {
    return (bid & 7) * 144 + (bid >> 3);
}

// k_prep: blocks [0,1152) transpose x -> channel-last bf16; [1152,1872) repack weights.
// [FROZEN r8]
__global__ __launch_bounds__(256)
void k_prep(const float* __restrict__ x,
            const float* __restrict__ offw, const float* __restrict__ modw,
            const float* __restrict__ weight,
            unsigned short* __restrict__ xb,
            unsigned short* __restrict__ wjT, unsigned short* __restrict__ wTA) {
    const int b = blockIdx.x;
    const int t = threadIdx.x;
    if (b < 1152) {
        __shared__ __align__(16) unsigned short lds[32][136];
        const int tile = swz_tile(b);           // write xb tiles on the XCD that reads them
        const int n = tile / 288, pix0 = (tile % 288) * 32;
        #pragma unroll
        for (int i = 0; i < 4; ++i) {
            const int c  = i*32 + (t >> 3);
            const int pb = (t & 7) * 4;
            const float4 v = *(const float4*)&x[((size_t)(n*C_ + c))*HW_ + pix0 + pb];
            lds[pb+0][c] = f2bf_rne(v.x);
            lds[pb+1][c] = f2bf_rne(v.y);
            lds[pb+2][c] = f2bf_rne(v.z);
            lds[pb+3][c] = f2bf_rne(v.w);
        }
        __syncthreads();
        #pragma unroll
        for (int it = 0; it < 2; ++it) {
            const int e = it*256 + t;
            const int p = e >> 4, g = e & 15;
            const uint4 v = *(const uint4*)&lds[p][g*8];
            *(uint4*)&xb[((size_t)n*HW_ + pix0 + p)*C_ + g*8] = v;
        }
    } else {
        const int e = (b - 1152)*256 + t;
        if (e < 36864) {
            const int k_lo = e & 7, j = (e >> 3) & 31, k_hi = (e >> 8) & 3, kk = e >> 10;
            const int c  = (kk & 3)*32 + k_hi*8 + k_lo;
            const int kt = kk >> 2;
            float v = 0.0f;
            if (j < 18)      v = offw[(j*C_ + c)*9 + kt];
            else if (j < 27) v = modw[((j-18)*C_ + c)*9 + kt];
            wjT[e] = f2bf_rne(v);
        } else {
            const int e2 = e - 36864;
            const int k_lo = e2 & 7, o = (e2 >> 3) & 127, k_hi = (e2 >> 10) & 3, kk = e2 >> 12;
            const int c  = (kk & 3)*32 + k_hi*8 + k_lo;
            const int kt = kk >> 2;
            wTA[e2] = f2bf_rne(weight[(o*C_ + c)*9 + kt]);
        }
    }
}

// k_offconv: K-split MFMA conv. Block = 32 px; 4 waves = 2 px-halves x 2 K-halves.
// grid 1152 -> 4608 waves (~18/CU). LDS pairwise reduction at the end. [FROZEN r6]
__global__ __launch_bounds__(256)
void k_offconv(const unsigned short* __restrict__ xb,
               const unsigned short* __restrict__ wjT,
               const float* __restrict__ offb, const float* __restrict__ modb,
               float* __restrict__ convout) {
    __shared__ float red[2][64][8];   // 4KB
    const int t = threadIdx.x;
    const int wid = t >> 6, lane = t & 63, quad = lane >> 4, l16 = lane & 15;
    const int ph = wid & 1, kh = wid >> 1;
    const int tile = swz_tile(blockIdx.x);
    const int n = tile / 288, p0 = (tile - n*288)*32;
    const int pix = p0 + ph*16 + l16;
    const int h = pix / W_, w = pix - h*W_;
    const unsigned short* xq = xb + ((size_t)n*HW_)*C_ + quad*8;

    f32x4 acc0 = {0.f,0.f,0.f,0.f};
    f32x4 acc1 = {0.f,0.f,0.f,0.f};

    #pragma unroll
    for (int i = 0; i < 18; ++i) {
        const int kk = kh*18 + i;
        const int kt = kk >> 2, s = kk & 3;
        const int dy = kt/3 - 1, dx = kt%3 - 1;
        const int y = h + dy, xx = w + dx;
        const bool valid = ((unsigned)y < H_) & ((unsigned)xx < W_);
        const uint4 braw = valid ? *(const uint4*)(xq + (size_t)(y*W_ + xx)*C_ + s*32)
                                 : make_uint4(0u,0u,0u,0u);
        const unsigned short* ap = wjT + (size_t)kk*1024 + quad*256 + l16*8;
        const bf16x8 a0 = *(const bf16x8*)(ap);
        const bf16x8 a1 = *(const bf16x8*)(ap + 128);
        const bf16x8 bfr = __builtin_bit_cast(bf16x8, braw);
        acc0 = __builtin_amdgcn_mfma_f32_16x16x32_bf16(a0, bfr, acc0, 0, 0, 0);
        acc1 = __builtin_amdgcn_mfma_f32_16x16x32_bf16(a1, bfr, acc1, 0, 0, 0);
    }

    if (kh == 1) {
        *(f32x4*)&red[ph][lane][0] = acc0;
        *(f32x4*)&red[ph][lane][4] = acc1;
    }
    __syncthreads();
    if (kh == 0) {
        const f32x4 r0 = *(const f32x4*)&red[ph][lane][0];
        const f32x4 r1 = *(const f32x4*)&red[ph][lane][4];
        #pragma unroll
        for (int r = 0; r < 4; ++r) {
            const int j0 = quad*4 + r;
            convout[((size_t)n*27 + j0)*HW_ + pix] =
                acc0[r] + r0[r] + (j0 < 18 ? offb[j0] : modb[j0-18]);
            const int j1 = 16 + quad*4 + r;
            if (j1 < 27)
                convout[((size_t)n*27 + j1)*HW_ + pix] = acc1[r] + r1[r] + modb[j1-18];
        }
    }
}

// k_gemm: r1/r6 fused tap-major pipelined loop + no-atomic partials epilogue.
// [FROZEN r6 — do not perturb codegen context]
__global__ __launch_bounds__(256)
void k_gemm(const unsigned short* __restrict__ xb,
            const float* __restrict__ convout,
            const unsigned short* __restrict__ wTA,
            unsigned short* __restrict__ out_pre,
            float* __restrict__ part) {
    __shared__ int4   midx[9][32];                            // 4.5KB corner byte offsets
    __shared__ float4 mwgt[9][32];                            // 4.5KB corner weights (mask folded)
    __shared__ __align__(16) unsigned short Blds[2][16][32][8]; // 16KB [buf][c4*quad4][px32^swz][8ch]

    const int t = threadIdx.x;
    const int wid = t >> 6, lane = t & 63, quad = lane >> 4, l16 = lane & 15;
    const int tile = swz_tile(blockIdx.x);
    const int n = tile / 288, p0 = (tile - n*288)*32;
    const char* xbn = (const char*)(xb + (size_t)n*HW_*C_);
    const float* co = convout + (size_t)n*27*HW_;

    // ---- Phase A: bilinear metadata for 9 taps x 32 pixels ----
    for (int it = t; it < 288; it += 256) {
        const int kt = it >> 5, p = it & 31;
        const int pix = p0 + p;
        const int h = pix / W_, w = pix - h*W_;
        const float offy = co[(2*kt  )*HW_ + pix];
        const float offx = co[(2*kt+1)*HW_ + pix];
        const float mraw = co[(18+kt )*HW_ + pix];
        const float m = 2.0f / (1.0f + __expf(-mraw));
        const float sy = offy + (float)(h + kt/3 - 1);
        const float sx = offx + (float)(w + kt%3 - 1);
        const float y0f = floorf(sy), x0f = floorf(sx);
        const float wy1 = sy - y0f, wx1 = sx - x0f;
        const float wyv[2] = {1.0f - wy1, wy1};
        const float wxv[2] = {1.0f - wx1, wx1};
        const float yfv[2] = {y0f, y0f + 1.0f};
        const float xfv[2] = {x0f, x0f + 1.0f};
        int   ii[4]; float ww[4];
        #pragma unroll
        for (int cy = 0; cy < 2; ++cy)
            #pragma unroll
            for (int cx = 0; cx < 2; ++cx) {
                const bool vld = (yfv[cy] >= 0.f) & (yfv[cy] <= (float)(H_-1)) &
                                 (xfv[cx] >= 0.f) & (xfv[cx] <= (float)(W_-1));
                const int yi = (int)fminf(fmaxf(yfv[cy], 0.f), (float)(H_-1));
                const int xi = (int)fminf(fmaxf(xfv[cx], 0.f), (float)(W_-1));
                ii[cy*2+cx] = (yi*W_ + xi)*C_*2;   // byte offset into xb row space
                ww[cy*2+cx] = vld ? wyv[cy]*wxv[cx]*m : 0.f;
            }
        midx[kt][p] = make_int4(ii[0], ii[1], ii[2], ii[3]);
        mwgt[kt][p] = make_float4(ww[0], ww[1], ww[2], ww[3]);
    }
    __syncthreads();

    f32x4 acc[2][2];
    #pragma unroll
    for (int i = 0; i < 2; ++i)
        #pragma unroll
        for (int j = 0; j < 2; ++j) acc[i][j] = (f32x4){0.f,0.f,0.f,0.f};

    // gather/blend thread mapping: px gp = t>>3, ch-group gg = t&7 (16 ch = 32B)
    const int gp = t >> 3;
    const int gg = t & 7;
    const int cb = gg >> 1;          // chunk-in-tap 0..3
    const int q2 = (gg & 1) * 2;     // quad base 0 or 2
    const char* xgg = xbn + gg*32;   // channel-slice base

    uint4 rr[4][2];                  // 4 corners x 32B in flight
    float4 wgn;

    auto gather_issue = [&](int kt) {
        const int4 ib = midx[kt][gp];
        wgn = mwgt[kt][gp];
        rr[0][0] = *(const uint4*)(xgg + ib.x); rr[0][1] = *(const uint4*)(xgg + ib.x + 16);
        rr[1][0] = *(const uint4*)(xgg + ib.y); rr[1][1] = *(const uint4*)(xgg + ib.y + 16);
        rr[2][0] = *(const uint4*)(xgg + ib.z); rr[2][1] = *(const uint4*)(xgg + ib.z + 16);
        rr[3][0] = *(const uint4*)(xgg + ib.w); rr[3][1] = *(const uint4*)(xgg + ib.w + 16);
    };
    auto blend_store = [&](int buf) {
        #pragma unroll
        for (int h = 0; h < 2; ++h) {
            const unsigned short* c0 = (const unsigned short*)&rr[0][h];
            const unsigned short* c1 = (const unsigned short*)&rr[1][h];
            const unsigned short* c2 = (const unsigned short*)&rr[2][h];
            const unsigned short* c3 = (const unsigned short*)&rr[3][h];
            ushortx8 v;
            #pragma unroll
            for (int j = 0; j < 8; ++j) {
                const float f = wgn.x*bf2f(c0[j]) + wgn.y*bf2f(c1[j])
                              + wgn.z*bf2f(c2[j]) + wgn.w*bf2f(c3[j]);
                v[j] = (unsigned short)(__builtin_bit_cast(unsigned, f) >> 16);
            }
            const int row = cb*4 + q2 + h;                    // [0,16)
            *(ushortx8*)&Blds[buf][row][gp ^ (row & 7)][0] = v;  // px-XOR: conflict-free
        }
    };

    // prologue: stage tap 0
    gather_issue(0);
    blend_store(0);
    __syncthreads();

    #pragma unroll 2
    for (int kt = 0; kt < 9; ++kt) {
        const int buf = kt & 1;
        // A fragments FIRST so the MFMA vmcnt-wait doesn't drain the gathers
        const unsigned short* ap = wTA + (size_t)kt*16384 + quad*1024 + (wid*32 + l16)*8;
        bf16x8 a[4][2];
        #pragma unroll
        for (int c = 0; c < 4; ++c) {
            a[c][0] = *(const bf16x8*)(ap + c*4096);
            a[c][1] = *(const bf16x8*)(ap + c*4096 + 128);
        }
        if (kt < 8) gather_issue(kt + 1);     // in flight across the MFMA block
        #pragma unroll
        for (int c = 0; c < 4; ++c) {
            const int row = c*4 + quad;
            const int sw = row & 7;
            const bf16x8 b0 = *(const bf16x8*)&Blds[buf][row][l16 ^ sw][0];
            const bf16x8 b1 = *(const bf16x8*)&Blds[buf][row][16 + (l16 ^ sw)][0];
            acc[0][0] = __builtin_amdgcn_mfma_f32_16x16x32_bf16(a[c][0], b0, acc[0][0], 0, 0, 0);
            acc[0][1] = __builtin_amdgcn_mfma_f32_16x16x32_bf16(a[c][0], b1, acc[0][1], 0, 0, 0);
            acc[1][0] = __builtin_amdgcn_mfma_f32_16x16x32_bf16(a[c][1], b0, acc[1][0], 0, 0, 0);
            acc[1][1] = __builtin_amdgcn_mfma_f32_16x16x32_bf16(a[c][1], b1, acc[1][1], 0, 0, 0);
        }
        if (kt < 8) blend_store(buf ^ 1);     // waits vmcnt(0) here, after MFMAs
        __syncthreads();                      // single barrier per tap (2-buffer safe)
    }

    // ---- epilogue: store pre-BN bf16; BN partials to private slots (no atomics) ----
    const int bid = blockIdx.x;
    #pragma unroll
    for (int mt = 0; mt < 2; ++mt) {
        #pragma unroll
        for (int r = 0; r < 4; ++r) {
            const int o = wid*32 + mt*16 + quad*4 + r;
            const float v0 = acc[mt][0][r];
            const float v1 = acc[mt][1][r];
            unsigned short* op = out_pre + ((size_t)n*CO_ + o)*HW_ + p0 + l16;
            op[0]  = f2bf_rne(v0);
            op[16] = f2bf_rne(v1);
            float s1 = v0 + v1, s2 = v0*v0 + v1*v1;
            #pragma unroll
            for (int d = 1; d < 16; d <<= 1) {
                s1 += __shfl_xor(s1, d);
                s2 += __shfl_xor(s2, d);
            }
            if (l16 == 0) {
                part[(size_t)o*1152 + bid]         = s1;
                part[(size_t)(128 + o)*1152 + bid] = s2;
            }
        }
    }
}

// k_red: reduce part[256][1152] -> bn[256]. One block per (stat,o); coalesced. [FROZEN r6]
__global__ __launch_bounds__(256)
void k_red(const float* __restrict__ part, float* __restrict__ bn) {
    __shared__ float red[4];
    const int b = blockIdx.x, t = threadIdx.x;
    float s = 0.f;
    for (int i = t; i < 1152; i += 256) s += part[(size_t)b*1152 + i];
    #pragma unroll
    for (int d = 1; d < 64; d <<= 1) s += __shfl_xor(s, d);
    if ((t & 63) == 0) red[t >> 6] = s;
    __syncthreads();
    if (t == 0) bn[b] = red[0] + red[1] + red[2] + red[3];
}

// k_bn: BN finalize + ReLU. 8 bf16 in, 8 f32 out per thread. [FROZEN r6]
__global__ __launch_bounds__(256)
void k_bn(const unsigned short* __restrict__ out_pre,
          const float* __restrict__ bnsum, const float* __restrict__ bnsq,
          const float* __restrict__ gamma, const float* __restrict__ beta,
          float* __restrict__ out) {
    const int e8 = blockIdx.x*256 + threadIdx.x;
    const int o = ((e8*8) / HW_) % CO_;
    const float invM = 1.0f / (float)(N_*HW_);
    const float mean = bnsum[o] * invM;
    const float var  = bnsq[o] * invM - mean*mean;
    const float gsc  = gamma[o] * rsqrtf(var + BN_EPS_);
    const float sh   = beta[o] - mean * gsc;
    const uint4 v = ((const uint4*)out_pre)[e8];
    const unsigned short* us = (const unsigned short*)&v;
    float4 o0, o1;
    o0.x = fmaxf(bf2f(us[0])*gsc + sh, 0.f);
    o0.y = fmaxf(bf2f(us[1])*gsc + sh, 0.f);
    o0.z = fmaxf(bf2f(us[2])*gsc + sh, 0.f);
    o0.w = fmaxf(bf2f(us[3])*gsc + sh, 0.f);
    o1.x = fmaxf(bf2f(us[4])*gsc + sh, 0.f);
    o1.y = fmaxf(bf2f(us[5])*gsc + sh, 0.f);
    o1.z = fmaxf(bf2f(us[6])*gsc + sh, 0.f);
    o1.w = fmaxf(bf2f(us[7])*gsc + sh, 0.f);
    ((float4*)out)[e8*2]     = o0;
    ((float4*)out)[e8*2 + 1] = o1;
}

extern "C" void kernel_launch(void* const* d_in, const int* in_sizes, int n_in,
                              void* d_out, int out_size, void* d_ws, size_t ws_size,
                              hipStream_t stream) {
    const float* x      = (const float*)d_in[0];
    const float* offw   = (const float*)d_in[1];
    const float* offb   = (const float*)d_in[2];
    const float* modw   = (const float*)d_in[3];
    const float* modb   = (const float*)d_in[4];
    const float* weight = (const float*)d_in[5];
    const float* gamma  = (const float*)d_in[7];
    const float* beta   = (const float*)d_in[8];
    float* out = (float*)d_out;

    float* wsf = (float*)d_ws;
    float*          convout = wsf + WS_CONVOUT;
    unsigned short* out_pre = (unsigned short*)(wsf + WS_OUTPRE);
    float*          bn      = wsf + WS_BN;
    unsigned short* wjT     = (unsigned short*)(wsf + WS_WJT);
    unsigned short* wTA     = (unsigned short*)(wsf + WS_WTA);
    unsigned short* xb      = (unsigned short*)(wsf + WS_XB);
    float*          part    = wsf + WS_PART;

    k_prep<<<1872, 256, 0, stream>>>(x, offw, modw, weight, xb, wjT, wTA);
    k_offconv<<<1152, 256, 0, stream>>>(xb, wjT, offb, modb, convout);
    k_gemm<<<1152, 256, 0, stream>>>(xb, convout, wTA, out_pre, part);
    k_red<<<256, 256, 0, stream>>>(part, bn);
    k_bn<<<2304, 256, 0, stream>>>(out_pre, bn, bn + 128, gamma, beta, out);
}